// Round 4
// baseline (105.042 us; speedup 1.0000x reference)
//
#include <hip/hip_runtime.h>

#define B     4096
#define KNB   64
#define D     128
#define NREL  32
#define EPS   1e-5f

typedef __attribute__((ext_vector_type(8))) short bf16x8;
typedef __attribute__((ext_vector_type(4))) float f32x4;

__device__ inline unsigned short f2bf(float f) {
    unsigned u = __float_as_uint(f);
    return (unsigned short)((u + 0x7FFFu + ((u >> 16) & 1u)) >> 16);
}
__device__ inline float bfu_lo(unsigned u) { return __uint_as_float(u << 16); }
__device__ inline float bfu_hi(unsigned u) { return __uint_as_float(u & 0xFFFF0000u); }

// tanh(x) = 1 - 2/(exp(2x)+1), exp via native v_exp_f32. |err| ~1e-6.
__device__ inline float fast_tanh(float x) {
    float e = __builtin_amdgcn_exp2f(x * 2.885390082f);   // 2*log2(e)
    return 1.f - 2.f * __builtin_amdgcn_rcpf(e + 1.f);
}

// ---------------------------------------------------------------------------
// prep: blocks 0..1023 -> h0 = bn(embs[{i,u}]);  block 1024 -> Wt = bf16(W^T)
// ---------------------------------------------------------------------------
__global__ __launch_bounds__(256) void prep(
    const int* __restrict__ i_idx, const int* __restrict__ u_idx,
    const float* __restrict__ embs,
    const float* __restrict__ gamma, const float* __restrict__ beta,
    const float* __restrict__ mean,  const float* __restrict__ var,
    float* __restrict__ h0,
    const float* __restrict__ W, unsigned short* __restrict__ Wt)
{
    const int t = threadIdx.x;
    if (blockIdx.x == 1024) {   // wt_prep
        #pragma unroll
        for (int m = 0; m < 64; ++m) {
            const int idx = m * 256 + t;
            const int k = idx >> 7, n = idx & 127;
            Wt[n * D + k] = f2bf(W[idx]);
        }
        return;
    }
    const int tid = blockIdx.x * 256 + t;      // 0 .. 2*B*32-1
    const int d4 = tid & 31;
    const int b  = (tid >> 5) & (B - 1);
    const int j  = tid >> 17;
    const int idx = j ? u_idx[b] : i_idx[b];

    const int d0 = d4 * 4;
    float4 x = *(const float4*)&embs[(size_t)idx * D + d0];
    float4 m = *(const float4*)&mean[d0];
    float4 v = *(const float4*)&var[d0];
    float4 g = *(const float4*)&gamma[d0];
    float4 bt = *(const float4*)&beta[d0];

    float4 o;
    o.x = (x.x - m.x) * g.x * rsqrtf(v.x + EPS) + bt.x;
    o.y = (x.y - m.y) * g.y * rsqrtf(v.y + EPS) + bt.y;
    o.z = (x.z - m.z) * g.z * rsqrtf(v.z + EPS) + bt.z;
    o.w = (x.w - m.w) * g.w * rsqrtf(v.w + EPS) + bt.w;

    *(float4*)&h0[(size_t)tid * 4] = o;
}

// ---------------------------------------------------------------------------
// Etr = bf16( in(f32) @ W + bias ), 16x16x32 bf16 MFMA.
// v2: A fragments loaded straight from global into registers (no A LDS);
// 32 KB W LDS (XOR-swizzled) reused as the epilogue store bounce.
// Block 256 thr (4 waves), tile 64 rows x 128 cols.
// ---------------------------------------------------------------------------
__global__ __launch_bounds__(256) void gemm_etr(
    const float* __restrict__ in, const unsigned short* __restrict__ Wt,
    const float* __restrict__ bias, unsigned short* __restrict__ outbf)
{
    __shared__ unsigned short Wl[128 * 128];   // 32 KB; reused for epilogue

    const int t = threadIdx.x;
    const size_t row0 = (size_t)blockIdx.x * 64;

    const int wv   = t >> 6;
    const int lane = t & 63;
    const int lrow = lane & 15;
    const int kgrp = lane >> 4;
    const int arow = wv * 16 + lrow;

    // A: 8 x float4 per lane = row (row0+arow), cols ks*32 + kgrp*8 + [0,8)
    float4 araw[8];
    {
        const float* base = in + (row0 + arow) * D + kgrp * 8;
        #pragma unroll
        for (int ks = 0; ks < 4; ++ks) {
            araw[2 * ks]     = *(const float4*)(base + ks * 32);
            araw[2 * ks + 1] = *(const float4*)(base + ks * 32 + 4);
        }
    }
    // stage Wt (bf16 [n][k]) -> LDS, swizzled
    {
        const float4* src = (const float4*)Wt;
        #pragma unroll
        for (int m = 0; m < 8; ++m) {
            const int c = m * 256 + t;
            const int n = c >> 4;
            float4 v = src[c];
            *(float4*)((char*)Wl + ((c * 16) ^ ((n & 7) << 4))) = v;
        }
    }
    __syncthreads();

    f32x4 acc[8];
    #pragma unroll
    for (int n = 0; n < 8; ++n) acc[n] = (f32x4){0.f, 0.f, 0.f, 0.f};

    #pragma unroll
    for (int ks = 0; ks < 4; ++ks) {
        union { bf16x8 v; unsigned short u[8]; } a;
        const float4 x = araw[2 * ks], y = araw[2 * ks + 1];
        a.u[0] = f2bf(x.x); a.u[1] = f2bf(x.y); a.u[2] = f2bf(x.z); a.u[3] = f2bf(x.w);
        a.u[4] = f2bf(y.x); a.u[5] = f2bf(y.y); a.u[6] = f2bf(y.z); a.u[7] = f2bf(y.w);
        #pragma unroll
        for (int n = 0; n < 8; ++n) {
            const int brow = n * 16 + lrow;
            const bf16x8 b = *(const bf16x8*)((const char*)Wl +
                ((brow * 256 + ks * 64 + kgrp * 16) ^ ((brow & 7) << 4)));
            acc[n] = __builtin_amdgcn_mfma_f32_16x16x32_bf16(a.v, b, acc[n], 0, 0, 0);
        }
    }

    __syncthreads();   // all waves done reading Wl
    // epilogue: acc+bias -> bf16 into Wl (swizzled), then coalesced store.
    // C/D layout: col = lane&15, row = (lane>>4)*4 + i
    #pragma unroll
    for (int n = 0; n < 8; ++n) {
        const float bv = bias[n * 16 + lrow];
        #pragma unroll
        for (int i = 0; i < 4; ++i) {
            const int r = wv * 16 + kgrp * 4 + i;
            const int cb = (r * 256 + (n * 16 + lrow) * 2) ^ ((r & 7) << 4);
            *(unsigned short*)((char*)Wl + cb) = f2bf(acc[n][i] + bv);
        }
    }
    __syncthreads();
    {
        float4* dst = (float4*)(outbf + row0 * D);
        #pragma unroll
        for (int m = 0; m < 4; ++m) {
            const int c = m * 256 + t;
            const int r = c >> 4;
            dst[c] = *(const float4*)((const char*)Wl + ((c * 16) ^ ((r & 7) << 4)));
        }
    }
}

// ---------------------------------------------------------------------------
// fp32 32-row x 128-col GEMM for the small (8192-row) matmuls.
// ---------------------------------------------------------------------------
__global__ __launch_bounds__(256) void gemm128(
    const float* __restrict__ in, const float* __restrict__ W,
    const float* __restrict__ bias, const float* __restrict__ add,
    float* __restrict__ out, int mode)
{
    __shared__ float Wl[128 * 128];
    __shared__ float inl[32 * 128];
    const int t = threadIdx.x;

    {
        const float4* W4 = (const float4*)W;
        float4* Wl4 = (float4*)Wl;
        #pragma unroll
        for (int m = 0; m < 16; ++m) Wl4[t + m * 256] = W4[t + m * 256];
    }
    const size_t row0 = (size_t)blockIdx.x * 32;
    {
        const float4* in4 = (const float4*)(in + row0 * D);
        float4* inl4 = (float4*)inl;
        #pragma unroll
        for (int m = 0; m < 4; ++m) inl4[t + m * 256] = in4[t + m * 256];
    }
    __syncthreads();

    const int c0 = (t & 31) * 4;
    const int r0 = (t >> 5) * 4;

    float acc[4][4];
    {
        float4 bv = *(const float4*)&bias[c0];
        #pragma unroll
        for (int i = 0; i < 4; ++i) {
            acc[i][0] = bv.x; acc[i][1] = bv.y; acc[i][2] = bv.z; acc[i][3] = bv.w;
        }
    }

    for (int k = 0; k < 128; k += 4) {
        float4 a[4], w[4];
        #pragma unroll
        for (int i = 0; i < 4; ++i) a[i] = *(const float4*)&inl[(r0 + i) * D + k];
        #pragma unroll
        for (int kk = 0; kk < 4; ++kk) w[kk] = *(const float4*)&Wl[(k + kk) * D + c0];
        #pragma unroll
        for (int i = 0; i < 4; ++i) {
            const float* ai = (const float*)&a[i];
            #pragma unroll
            for (int kk = 0; kk < 4; ++kk) {
                acc[i][0] = fmaf(ai[kk], w[kk].x, acc[i][0]);
                acc[i][1] = fmaf(ai[kk], w[kk].y, acc[i][1]);
                acc[i][2] = fmaf(ai[kk], w[kk].z, acc[i][2]);
                acc[i][3] = fmaf(ai[kk], w[kk].w, acc[i][3]);
            }
        }
    }

    #pragma unroll
    for (int i = 0; i < 4; ++i) {
        const size_t r = row0 + r0 + i;
        float4 o = make_float4(acc[i][0], acc[i][1], acc[i][2], acc[i][3]);
        if (mode == 1) {
            float4 ad = *(const float4*)&add[r * D + c0];
            o.x = ad.x + (o.x >= 0.f ? o.x : 0.2f * o.x);
            o.y = ad.y + (o.y >= 0.f ? o.y : 0.2f * o.y);
            o.z = ad.z + (o.z >= 0.f ? o.z : 0.2f * o.z);
            o.w = ad.w + (o.w >= 0.f ? o.w : 0.2f * o.w);
        }
        *(float4*)&out[r * D + c0] = o;
    }
}

// ---------------------------------------------------------------------------
// aggregate v3: one barrier, in-wave shuffle reduce, 32 waves/CU.
// grp = t&7 (K-slice), dq = t>>3 (dim quad). Lanes t^{1,2,4} share dq.
// ---------------------------------------------------------------------------
__global__ __launch_bounds__(256) void aggregate(
    const int* __restrict__ i_idx, const int* __restrict__ u_idx,
    const int* __restrict__ adj_e, const int* __restrict__ adj_r,
    const unsigned short* __restrict__ Etr, const float* __restrict__ rel_embs,
    const float* __restrict__ hW,  const float* __restrict__ h0,
    float* __restrict__ g_out)
{
    __shared__ float tt[NREL * D];    // 16 KB
    __shared__ int ents[KNB];         // byte offsets into Etr
    __shared__ int rels[KNB];         // byte offsets into tt

    const int t = threadIdx.x;
    const int b = blockIdx.x & (B - 1);
    const int j = blockIdx.x >> 12;
    const size_t rowbase = ((size_t)j * B + b) * D;
    const int idx = j ? u_idx[b] : i_idx[b];

    if (t < KNB) {
        ents[t] = adj_e[(size_t)idx * KNB + t] * (D * 2);
        rels[t] = adj_r[(size_t)idx * KNB + t] * (D * 4);
    }
    // tanh table: 4 float4/thread; hW chunk is constant per thread (t&31)
    {
        const float4 hv = *(const float4*)&hW[rowbase + (t & 31) * 4];
        const float4* re4 = (const float4*)rel_embs;
        #pragma unroll
        for (int c = 0; c < 4; ++c) {
            const int m4 = t + c * 256;
            const float4 r = re4[m4];
            float4 o;
            o.x = fast_tanh(hv.x + r.x);
            o.y = fast_tanh(hv.y + r.y);
            o.z = fast_tanh(hv.z + r.z);
            o.w = fast_tanh(hv.w + r.w);
            *(float4*)&tt[m4 * 4] = o;
        }
    }
    __syncthreads();

    const int grp = t & 7;
    const int dq  = t >> 3;       // 0..31 : dims 4*dq .. 4*dq+3
    const char* Eb = (const char*)Etr + dq * 8;
    const char* tb = (const char*)tt  + dq * 16;

    float s0 = 0.f, s1 = 0.f, s2 = 0.f, s3 = 0.f;
    float q0 = 0.f, q1 = 0.f, q2 = 0.f, q3 = 0.f;
    #pragma unroll
    for (int it = 0; it < 8; ++it) {
        const int k = grp + it * 8;
        const uint2  ev = *(const uint2*)(Eb + ents[k]);
        const float4 tv = *(const float4*)(tb + rels[k]);
        const float v0 = bfu_lo(ev.x) * tv.x;
        const float v1 = bfu_hi(ev.x) * tv.y;
        const float v2 = bfu_lo(ev.y) * tv.z;
        const float v3 = bfu_hi(ev.y) * tv.w;
        s0 += v0; s1 += v1; s2 += v2; s3 += v3;
        q0 = fmaf(v0, v0, q0); q1 = fmaf(v1, v1, q1);
        q2 = fmaf(v2, v2, q2); q3 = fmaf(v3, v3, q3);
    }
    #pragma unroll
    for (int off = 1; off <= 4; off <<= 1) {
        s0 += __shfl_xor(s0, off); s1 += __shfl_xor(s1, off);
        s2 += __shfl_xor(s2, off); s3 += __shfl_xor(s3, off);
        q0 += __shfl_xor(q0, off); q1 += __shfl_xor(q1, off);
        q2 += __shfl_xor(q2, off); q3 += __shfl_xor(q3, off);
    }
    if (grp == 0) {
        const float4 h = *(const float4*)&h0[rowbase + dq * 4];
        float4 o;
        o.x = h.x + s0 * s0 - q0;
        o.y = h.y + s1 * s1 - q1;
        o.z = h.z + s2 * s2 - q2;
        o.w = h.w + s3 * s3 - q3;
        *(float4*)&g_out[rowbase + dq * 4] = o;
    }
}

// ---------------------------------------------------------------------------
// out[b] = u_e[b]·wl[0:128] + h[b]·wl[128:256] + wl_b
// ---------------------------------------------------------------------------
__global__ __launch_bounds__(256) void final_dot(
    const float* __restrict__ hfin, const float* __restrict__ wl_w,
    const float* __restrict__ wl_b, float* __restrict__ out)
{
    const int t = threadIdx.x;
    const int w = t >> 6;
    const int lane = t & 63;
    const int b = blockIdx.x * 4 + w;

    const float* hu = hfin + ((size_t)B + b) * D;
    const float* hh = hfin + (size_t)b * D;

    float v = hu[lane]      * wl_w[lane]
            + hu[lane + 64] * wl_w[lane + 64]
            + hh[lane]      * wl_w[128 + lane]
            + hh[lane + 64] * wl_w[192 + lane];
    #pragma unroll
    for (int off = 32; off; off >>= 1) v += __shfl_xor(v, off);
    if (lane == 0) out[b] = v + wl_b[0];
}

extern "C" void kernel_launch(void* const* d_in, const int* in_sizes, int n_in,
                              void* d_out, int out_size, void* d_ws, size_t ws_size,
                              hipStream_t stream) {
    const int*   u        = (const int*)d_in[0];
    const int*   ii       = (const int*)d_in[1];
    const int*   adj_e    = (const int*)d_in[2];
    const int*   adj_r    = (const int*)d_in[3];
    const float* embs     = (const float*)d_in[4];
    const float* rel_embs = (const float*)d_in[5];
    const float* gamma    = (const float*)d_in[6];
    const float* beta     = (const float*)d_in[7];
    const float* mean     = (const float*)d_in[8];
    const float* var      = (const float*)d_in[9];
    const float* Wr1_w    = (const float*)d_in[10];
    const float* Wr1_b    = (const float*)d_in[11];
    const float* W1_w     = (const float*)d_in[12];
    const float* W1_b     = (const float*)d_in[13];
    const float* wl_w     = (const float*)d_in[14];
    const float* wl_b     = (const float*)d_in[15];
    float* out = (float*)d_out;

    const int n_ent = in_sizes[2] / KNB;    // 200000

    char* p = (char*)d_ws;
    unsigned short* Etr = (unsigned short*)p;           p += (size_t)n_ent * D * 2;   // 51.2 MB
    unsigned short* Wt  = (unsigned short*)p;           p += (size_t)D * D * 2;       // 32 KB
    float* h0   = (float*)p;                            p += (size_t)2 * B * D * 4;
    float* hWb  = (float*)p;                            p += (size_t)2 * B * D * 4;
    float* gb   = (float*)p;                            p += (size_t)2 * B * D * 4;
    float* hfin = (float*)p;

    // 1. h0 = bn(embs[{i,u}])  +  Wt = bf16(Wr1^T)
    prep<<<1025, 256, 0, stream>>>(ii, u, embs, gamma, beta, mean, var, h0, Wr1_w, Wt);
    // 2. hW = h0 @ Wr1 + b   (fp32, small)
    gemm128<<<(2 * B) / 32, 256, 0, stream>>>(h0, Wr1_w, Wr1_b, nullptr, hWb, 0);
    // 3. Etr = bf16(embs @ Wr1 + b)   (MFMA)
    gemm_etr<<<n_ent / 64, 256, 0, stream>>>(embs, Wt, Wr1_b, Etr);
    // 4. FM aggregation -> g = h0 + Nh
    aggregate<<<2 * B, 256, 0, stream>>>(ii, u, adj_e, adj_r, Etr, rel_embs, hWb, h0, gb);
    // 5. hfin = h0 + lrelu(g @ W1 + b)
    gemm128<<<(2 * B) / 32, 256, 0, stream>>>(gb, W1_w, W1_b, h0, hfin, 1);
    // 6. out = [u_e, h] @ wl + b
    final_dot<<<B / 4, 256, 0, stream>>>(hfin, wl_w, wl_b, out);
}

// Round 5
// 92.551 us; speedup vs baseline: 1.1350x; 1.1350x over previous
//
#include <hip/hip_runtime.h>

#define B     4096
#define KNB   64
#define D     128
#define NREL  32
#define EPS   1e-5f

typedef __attribute__((ext_vector_type(8))) short bf16x8;
typedef __attribute__((ext_vector_type(4))) float f32x4;

__device__ inline unsigned short f2bf(float f) {
    unsigned u = __float_as_uint(f);
    return (unsigned short)((u + 0x7FFFu + ((u >> 16) & 1u)) >> 16);
}
__device__ inline float bfu_lo(unsigned u) { return __uint_as_float(u << 16); }
__device__ inline float bfu_hi(unsigned u) { return __uint_as_float(u & 0xFFFF0000u); }

// tanh(x) = 1 - 2/(exp(2x)+1), exp via native v_exp_f32. |err| ~1e-6.
__device__ inline float fast_tanh(float x) {
    float e = __builtin_amdgcn_exp2f(x * 2.885390082f);   // 2*log2(e)
    return 1.f - 2.f * __builtin_amdgcn_rcpf(e + 1.f);
}

// ---------------------------------------------------------------------------
// prep: blocks 0..1023 -> h0 = bn(embs[{i,u}]);  block 1024 -> Wt = bf16(W^T)
// ---------------------------------------------------------------------------
__global__ __launch_bounds__(256) void prep(
    const int* __restrict__ i_idx, const int* __restrict__ u_idx,
    const float* __restrict__ embs,
    const float* __restrict__ gamma, const float* __restrict__ beta,
    const float* __restrict__ mean,  const float* __restrict__ var,
    float* __restrict__ h0,
    const float* __restrict__ W, unsigned short* __restrict__ Wt)
{
    const int t = threadIdx.x;
    if (blockIdx.x == 1024) {   // wt_prep
        #pragma unroll
        for (int m = 0; m < 64; ++m) {
            const int idx = m * 256 + t;
            const int k = idx >> 7, n = idx & 127;
            Wt[n * D + k] = f2bf(W[idx]);
        }
        return;
    }
    const int tid = blockIdx.x * 256 + t;      // 0 .. 2*B*32-1
    const int d4 = tid & 31;
    const int b  = (tid >> 5) & (B - 1);
    const int j  = tid >> 17;
    const int idx = j ? u_idx[b] : i_idx[b];

    const int d0 = d4 * 4;
    float4 x = *(const float4*)&embs[(size_t)idx * D + d0];
    float4 m = *(const float4*)&mean[d0];
    float4 v = *(const float4*)&var[d0];
    float4 g = *(const float4*)&gamma[d0];
    float4 bt = *(const float4*)&beta[d0];

    float4 o;
    o.x = (x.x - m.x) * g.x * rsqrtf(v.x + EPS) + bt.x;
    o.y = (x.y - m.y) * g.y * rsqrtf(v.y + EPS) + bt.y;
    o.z = (x.z - m.z) * g.z * rsqrtf(v.z + EPS) + bt.z;
    o.w = (x.w - m.w) * g.w * rsqrtf(v.w + EPS) + bt.w;

    *(float4*)&h0[(size_t)tid * 4] = o;
}

// ---------------------------------------------------------------------------
// Etr = bf16( in(f32) @ W + bias ), 16x16x32 bf16 MFMA.  (R2-proven version)
// Block 256 thr (4 waves), tile 64 rows x 128 cols; XOR-swizzled LDS.
// ---------------------------------------------------------------------------
__global__ __launch_bounds__(256) void gemm_etr(
    const float* __restrict__ in, const unsigned short* __restrict__ Wt,
    const float* __restrict__ bias, unsigned short* __restrict__ outbf)
{
    __shared__ unsigned short Al[64 * 128];    // 16 KB
    __shared__ unsigned short Wl[128 * 128];   // 32 KB

    const int t = threadIdx.x;
    const size_t row0 = (size_t)blockIdx.x * 64;

    {
        const float4* src = (const float4*)Wt;
        #pragma unroll
        for (int m = 0; m < 8; ++m) {
            const int c = m * 256 + t;
            const int n = c >> 4;
            float4 v = src[c];
            *(float4*)((char*)Wl + ((c * 16) ^ ((n & 7) << 4))) = v;
        }
    }
    {
        #pragma unroll
        for (int m = 0; m < 4; ++m) {
            const int c = m * 256 + t;
            const int r = c >> 4;
            const int k0 = (c & 15) * 8;
            const float4* s = (const float4*)&in[(row0 + r) * D + k0];
            const float4 x = s[0], y = s[1];
            alignas(16) unsigned short h[8] = {
                f2bf(x.x), f2bf(x.y), f2bf(x.z), f2bf(x.w),
                f2bf(y.x), f2bf(y.y), f2bf(y.z), f2bf(y.w) };
            *(float4*)((char*)Al + ((r * 256 + k0 * 2) ^ ((r & 7) << 4))) =
                *(const float4*)h;
        }
    }
    __syncthreads();

    const int wv   = t >> 6;
    const int lane = t & 63;
    const int rw   = wv * 16;
    const int lrow = lane & 15;
    const int kgrp = lane >> 4;

    f32x4 acc[8];
    #pragma unroll
    for (int n = 0; n < 8; ++n) acc[n] = (f32x4){0.f, 0.f, 0.f, 0.f};

    #pragma unroll
    for (int ks = 0; ks < 4; ++ks) {
        const int arow = rw + lrow;
        const bf16x8 a = *(const bf16x8*)((const char*)Al +
            ((arow * 256 + ks * 64 + kgrp * 16) ^ ((arow & 7) << 4)));
        #pragma unroll
        for (int n = 0; n < 8; ++n) {
            const int brow = n * 16 + lrow;
            const bf16x8 b = *(const bf16x8*)((const char*)Wl +
                ((brow * 256 + ks * 64 + kgrp * 16) ^ ((brow & 7) << 4)));
            acc[n] = __builtin_amdgcn_mfma_f32_16x16x32_bf16(a, b, acc[n], 0, 0, 0);
        }
    }

    __syncthreads();
    // C/D layout: col = lane&15, row = (lane>>4)*4 + i
    #pragma unroll
    for (int n = 0; n < 8; ++n) {
        const float bv = bias[n * 16 + lrow];
        #pragma unroll
        for (int i = 0; i < 4; ++i) {
            const int r = rw + kgrp * 4 + i;
            const int cb = (r * 256 + (n * 16 + lrow) * 2) ^ ((r & 7) << 4);
            *(unsigned short*)((char*)Al + cb) = f2bf(acc[n][i] + bv);
        }
    }
    __syncthreads();
    {
        float4* dst = (float4*)(outbf + row0 * D);
        #pragma unroll
        for (int m = 0; m < 4; ++m) {
            const int c = m * 256 + t;
            const int r = c >> 4;
            dst[c] = *(const float4*)((const char*)Al + ((c * 16) ^ ((r & 7) << 4)));
        }
    }
}

// ---------------------------------------------------------------------------
// fp32 32-row x 128-col GEMM for the small (8192-row) matmuls.
// ---------------------------------------------------------------------------
__global__ __launch_bounds__(256) void gemm128(
    const float* __restrict__ in, const float* __restrict__ W,
    const float* __restrict__ bias, const float* __restrict__ add,
    float* __restrict__ out, int mode)
{
    __shared__ float Wl[128 * 128];
    __shared__ float inl[32 * 128];
    const int t = threadIdx.x;

    {
        const float4* W4 = (const float4*)W;
        float4* Wl4 = (float4*)Wl;
        #pragma unroll
        for (int m = 0; m < 16; ++m) Wl4[t + m * 256] = W4[t + m * 256];
    }
    const size_t row0 = (size_t)blockIdx.x * 32;
    {
        const float4* in4 = (const float4*)(in + row0 * D);
        float4* inl4 = (float4*)inl;
        #pragma unroll
        for (int m = 0; m < 4; ++m) inl4[t + m * 256] = in4[t + m * 256];
    }
    __syncthreads();

    const int c0 = (t & 31) * 4;
    const int r0 = (t >> 5) * 4;

    float acc[4][4];
    {
        float4 bv = *(const float4*)&bias[c0];
        #pragma unroll
        for (int i = 0; i < 4; ++i) {
            acc[i][0] = bv.x; acc[i][1] = bv.y; acc[i][2] = bv.z; acc[i][3] = bv.w;
        }
    }

    for (int k = 0; k < 128; k += 4) {
        float4 a[4], w[4];
        #pragma unroll
        for (int i = 0; i < 4; ++i) a[i] = *(const float4*)&inl[(r0 + i) * D + k];
        #pragma unroll
        for (int kk = 0; kk < 4; ++kk) w[kk] = *(const float4*)&Wl[(k + kk) * D + c0];
        #pragma unroll
        for (int i = 0; i < 4; ++i) {
            const float* ai = (const float*)&a[i];
            #pragma unroll
            for (int kk = 0; kk < 4; ++kk) {
                acc[i][0] = fmaf(ai[kk], w[kk].x, acc[i][0]);
                acc[i][1] = fmaf(ai[kk], w[kk].y, acc[i][1]);
                acc[i][2] = fmaf(ai[kk], w[kk].z, acc[i][2]);
                acc[i][3] = fmaf(ai[kk], w[kk].w, acc[i][3]);
            }
        }
    }

    #pragma unroll
    for (int i = 0; i < 4; ++i) {
        const size_t r = row0 + r0 + i;
        float4 o = make_float4(acc[i][0], acc[i][1], acc[i][2], acc[i][3]);
        if (mode == 1) {
            float4 ad = *(const float4*)&add[r * D + c0];
            o.x = ad.x + (o.x >= 0.f ? o.x : 0.2f * o.x);
            o.y = ad.y + (o.y >= 0.f ? o.y : 0.2f * o.y);
            o.z = ad.z + (o.z >= 0.f ? o.z : 0.2f * o.z);
            o.w = ad.w + (o.w >= 0.f ? o.w : 0.2f * o.w);
        }
        *(float4*)&out[r * D + c0] = o;
    }
}

// ---------------------------------------------------------------------------
// aggregate v4: proven gather layout (dq=t&31 -> full 256B Etr rows/instr),
// in-wave shfl_xor(32) fold -> ps[4] LDS -> final. 20.5 KB LDS, 2 barriers.
// ---------------------------------------------------------------------------
__global__ __launch_bounds__(256) void aggregate(
    const int* __restrict__ i_idx, const int* __restrict__ u_idx,
    const int* __restrict__ adj_e, const int* __restrict__ adj_r,
    const unsigned short* __restrict__ Etr, const float* __restrict__ rel_embs,
    const float* __restrict__ hW,  const float* __restrict__ h0,
    float* __restrict__ g_out)
{
    __shared__ float tt[NREL * D];    // 16 KB
    __shared__ int ents[KNB];         // byte offsets into Etr
    __shared__ int rels[KNB];         // byte offsets into tt
    __shared__ float ps[4][D];        // 2 KB
    __shared__ float pq[4][D];        // 2 KB

    const int t = threadIdx.x;
    const int b = blockIdx.x & (B - 1);
    const int j = blockIdx.x >> 12;
    const size_t rowbase = ((size_t)j * B + b) * D;
    const int idx = j ? u_idx[b] : i_idx[b];

    if (t < KNB) {
        ents[t] = adj_e[(size_t)idx * KNB + t] * (D * 2);
        rels[t] = adj_r[(size_t)idx * KNB + t] * (D * 4);
    }
    // tanh table: 4 float4/thread; hW chunk is constant per thread (t&31)
    {
        const float4 hv = *(const float4*)&hW[rowbase + (t & 31) * 4];
        const float4* re4 = (const float4*)rel_embs;
        #pragma unroll
        for (int c = 0; c < 4; ++c) {
            const int m4 = t + c * 256;
            const float4 r = re4[m4];
            float4 o;
            o.x = fast_tanh(hv.x + r.x);
            o.y = fast_tanh(hv.y + r.y);
            o.z = fast_tanh(hv.z + r.z);
            o.w = fast_tanh(hv.w + r.w);
            *(float4*)&tt[m4 * 4] = o;
        }
    }
    __syncthreads();

    const int dq  = t & 31;       // dims 4*dq .. 4*dq+3 (full row per half-wave)
    const int grp = t >> 5;       // 0..7, K-slice
    const char* Eb = (const char*)Etr + dq * 8;
    const char* tb = (const char*)tt  + dq * 16;

    float s0 = 0.f, s1 = 0.f, s2 = 0.f, s3 = 0.f;
    float q0 = 0.f, q1 = 0.f, q2 = 0.f, q3 = 0.f;
    #pragma unroll
    for (int it = 0; it < 8; ++it) {
        const int k = grp + it * 8;
        const uint2  ev = *(const uint2*)(Eb + ents[k]);
        const float4 tv = *(const float4*)(tb + rels[k]);
        const float v0 = bfu_lo(ev.x) * tv.x;
        const float v1 = bfu_hi(ev.x) * tv.y;
        const float v2 = bfu_lo(ev.y) * tv.z;
        const float v3 = bfu_hi(ev.y) * tv.w;
        s0 += v0; s1 += v1; s2 += v2; s3 += v3;
        q0 = fmaf(v0, v0, q0); q1 = fmaf(v1, v1, q1);
        q2 = fmaf(v2, v2, q2); q3 = fmaf(v3, v3, q3);
    }
    // fold the wave's two grp halves (lane ^ 32)
    s0 += __shfl_xor(s0, 32); s1 += __shfl_xor(s1, 32);
    s2 += __shfl_xor(s2, 32); s3 += __shfl_xor(s3, 32);
    q0 += __shfl_xor(q0, 32); q1 += __shfl_xor(q1, 32);
    q2 += __shfl_xor(q2, 32); q3 += __shfl_xor(q3, 32);

    const int wv = t >> 6;
    if ((t & 63) < 32) {
        *(float4*)&ps[wv][dq * 4] = make_float4(s0, s1, s2, s3);
        *(float4*)&pq[wv][dq * 4] = make_float4(q0, q1, q2, q3);
    }
    __syncthreads();

    if (t < D) {
        const float ss = ps[0][t] + ps[1][t] + ps[2][t] + ps[3][t];
        const float qq = pq[0][t] + pq[1][t] + pq[2][t] + pq[3][t];
        g_out[rowbase + t] = h0[rowbase + t] + ss * ss - qq;
    }
}

// ---------------------------------------------------------------------------
// out[b] = u_e[b]·wl[0:128] + h[b]·wl[128:256] + wl_b
// ---------------------------------------------------------------------------
__global__ __launch_bounds__(256) void final_dot(
    const float* __restrict__ hfin, const float* __restrict__ wl_w,
    const float* __restrict__ wl_b, float* __restrict__ out)
{
    const int t = threadIdx.x;
    const int w = t >> 6;
    const int lane = t & 63;
    const int b = blockIdx.x * 4 + w;

    const float* hu = hfin + ((size_t)B + b) * D;
    const float* hh = hfin + (size_t)b * D;

    float v = hu[lane]      * wl_w[lane]
            + hu[lane + 64] * wl_w[lane + 64]
            + hh[lane]      * wl_w[128 + lane]
            + hh[lane + 64] * wl_w[192 + lane];
    #pragma unroll
    for (int off = 32; off; off >>= 1) v += __shfl_xor(v, off);
    if (lane == 0) out[b] = v + wl_b[0];
}

extern "C" void kernel_launch(void* const* d_in, const int* in_sizes, int n_in,
                              void* d_out, int out_size, void* d_ws, size_t ws_size,
                              hipStream_t stream) {
    const int*   u        = (const int*)d_in[0];
    const int*   ii       = (const int*)d_in[1];
    const int*   adj_e    = (const int*)d_in[2];
    const int*   adj_r    = (const int*)d_in[3];
    const float* embs     = (const float*)d_in[4];
    const float* rel_embs = (const float*)d_in[5];
    const float* gamma    = (const float*)d_in[6];
    const float* beta     = (const float*)d_in[7];
    const float* mean     = (const float*)d_in[8];
    const float* var      = (const float*)d_in[9];
    const float* Wr1_w    = (const float*)d_in[10];
    const float* Wr1_b    = (const float*)d_in[11];
    const float* W1_w     = (const float*)d_in[12];
    const float* W1_b     = (const float*)d_in[13];
    const float* wl_w     = (const float*)d_in[14];
    const float* wl_b     = (const float*)d_in[15];
    float* out = (float*)d_out;

    const int n_ent = in_sizes[2] / KNB;    // 200000

    char* p = (char*)d_ws;
    unsigned short* Etr = (unsigned short*)p;           p += (size_t)n_ent * D * 2;   // 51.2 MB
    unsigned short* Wt  = (unsigned short*)p;           p += (size_t)D * D * 2;       // 32 KB
    float* h0   = (float*)p;                            p += (size_t)2 * B * D * 4;
    float* hWb  = (float*)p;                            p += (size_t)2 * B * D * 4;
    float* gb   = (float*)p;                            p += (size_t)2 * B * D * 4;
    float* hfin = (float*)p;

    // 1. h0 = bn(embs[{i,u}])  +  Wt = bf16(Wr1^T)
    prep<<<1025, 256, 0, stream>>>(ii, u, embs, gamma, beta, mean, var, h0, Wr1_w, Wt);
    // 2. hW = h0 @ Wr1 + b   (fp32, small)
    gemm128<<<(2 * B) / 32, 256, 0, stream>>>(h0, Wr1_w, Wr1_b, nullptr, hWb, 0);
    // 3. Etr = bf16(embs @ Wr1 + b)   (MFMA)
    gemm_etr<<<n_ent / 64, 256, 0, stream>>>(embs, Wt, Wr1_b, Etr);
    // 4. FM aggregation -> g = h0 + Nh
    aggregate<<<2 * B, 256, 0, stream>>>(ii, u, adj_e, adj_r, Etr, rel_embs, hWb, h0, gb);
    // 5. hfin = h0 + lrelu(g @ W1 + b)
    gemm128<<<(2 * B) / 32, 256, 0, stream>>>(gb, W1_w, W1_b, h0, hfin, 1);
    // 6. out = [u_e, h] @ wl + b
    final_dot<<<B / 4, 256, 0, stream>>>(hfin, wl_w, wl_b, out);
}

// Round 6
// 82.417 us; speedup vs baseline: 1.2745x; 1.1230x over previous
//
#include <hip/hip_runtime.h>

#define B     4096
#define KNB   64
#define D     128
#define NREL  32
#define EPS   1e-5f

typedef __attribute__((ext_vector_type(8))) short bf16x8;
typedef __attribute__((ext_vector_type(4))) float f32x4;

__device__ inline unsigned short f2bf(float f) {
    unsigned u = __float_as_uint(f);
    return (unsigned short)((u + 0x7FFFu + ((u >> 16) & 1u)) >> 16);
}
__device__ inline float bfu_lo(unsigned u) { return __uint_as_float(u << 16); }
__device__ inline float bfu_hi(unsigned u) { return __uint_as_float(u & 0xFFFF0000u); }

// tanh(x) = 1 - 2/(exp(2x)+1), exp via native v_exp_f32. |err| ~1e-6.
__device__ inline float fast_tanh(float x) {
    float e = __builtin_amdgcn_exp2f(x * 2.885390082f);   // 2*log2(e)
    return 1.f - 2.f * __builtin_amdgcn_rcpf(e + 1.f);
}

// ---------------------------------------------------------------------------
// prep: blocks 0..1023 -> h0 = bn(embs[{i,u}]);  block 1024 -> Wt = bf16(W^T)
// ---------------------------------------------------------------------------
__global__ __launch_bounds__(256) void prep(
    const int* __restrict__ i_idx, const int* __restrict__ u_idx,
    const float* __restrict__ embs,
    const float* __restrict__ gamma, const float* __restrict__ beta,
    const float* __restrict__ mean,  const float* __restrict__ var,
    float* __restrict__ h0,
    const float* __restrict__ W, unsigned short* __restrict__ Wt)
{
    const int t = threadIdx.x;
    if (blockIdx.x == 1024) {   // wt_prep
        #pragma unroll
        for (int m = 0; m < 64; ++m) {
            const int idx = m * 256 + t;
            const int k = idx >> 7, n = idx & 127;
            Wt[n * D + k] = f2bf(W[idx]);
        }
        return;
    }
    const int tid = blockIdx.x * 256 + t;      // 0 .. 2*B*32-1
    const int d4 = tid & 31;
    const int b  = (tid >> 5) & (B - 1);
    const int j  = tid >> 17;
    const int idx = j ? u_idx[b] : i_idx[b];

    const int d0 = d4 * 4;
    float4 x = *(const float4*)&embs[(size_t)idx * D + d0];
    float4 m = *(const float4*)&mean[d0];
    float4 v = *(const float4*)&var[d0];
    float4 g = *(const float4*)&gamma[d0];
    float4 bt = *(const float4*)&beta[d0];

    float4 o;
    o.x = (x.x - m.x) * g.x * rsqrtf(v.x + EPS) + bt.x;
    o.y = (x.y - m.y) * g.y * rsqrtf(v.y + EPS) + bt.y;
    o.z = (x.z - m.z) * g.z * rsqrtf(v.z + EPS) + bt.z;
    o.w = (x.w - m.w) * g.w * rsqrtf(v.w + EPS) + bt.w;

    *(float4*)&h0[(size_t)tid * 4] = o;
}

// ---------------------------------------------------------------------------
// MFMA GEMM, 16x16x32 bf16, tile 64 rows x 128 cols, 4 waves.
// blocks <  nb1 : Etr  = bf16( in  @ W + bias )  (bf16 bounce-store)
// blocks >= nb1 : hW   =        in2 @ W + bias   (f32 direct store)
// ---------------------------------------------------------------------------
__global__ __launch_bounds__(256) void gemm_etr(
    const float* __restrict__ in, const unsigned short* __restrict__ Wt,
    const float* __restrict__ bias, unsigned short* __restrict__ outbf,
    const float* __restrict__ in2, float* __restrict__ out2, int nb1)
{
    __shared__ unsigned short Al[64 * 128];    // 16 KB
    __shared__ unsigned short Wl[128 * 128];   // 32 KB

    const int t = threadIdx.x;
    const bool second = (int)blockIdx.x >= nb1;
    const float* src = second ? in2 : in;
    const size_t row0 = (size_t)(second ? (int)blockIdx.x - nb1 : (int)blockIdx.x) * 64;

    {
        const float4* w4 = (const float4*)Wt;
        #pragma unroll
        for (int m = 0; m < 8; ++m) {
            const int c = m * 256 + t;
            const int n = c >> 4;
            float4 v = w4[c];
            *(float4*)((char*)Wl + ((c * 16) ^ ((n & 7) << 4))) = v;
        }
    }
    {
        #pragma unroll
        for (int m = 0; m < 4; ++m) {
            const int c = m * 256 + t;
            const int r = c >> 4;
            const int k0 = (c & 15) * 8;
            const float4* s = (const float4*)&src[(row0 + r) * D + k0];
            const float4 x = s[0], y = s[1];
            alignas(16) unsigned short h[8] = {
                f2bf(x.x), f2bf(x.y), f2bf(x.z), f2bf(x.w),
                f2bf(y.x), f2bf(y.y), f2bf(y.z), f2bf(y.w) };
            *(float4*)((char*)Al + ((r * 256 + k0 * 2) ^ ((r & 7) << 4))) =
                *(const float4*)h;
        }
    }
    __syncthreads();

    const int wv   = t >> 6;
    const int lane = t & 63;
    const int rw   = wv * 16;
    const int lrow = lane & 15;
    const int kgrp = lane >> 4;

    f32x4 acc[8];
    #pragma unroll
    for (int n = 0; n < 8; ++n) acc[n] = (f32x4){0.f, 0.f, 0.f, 0.f};

    #pragma unroll
    for (int ks = 0; ks < 4; ++ks) {
        const int arow = rw + lrow;
        const bf16x8 a = *(const bf16x8*)((const char*)Al +
            ((arow * 256 + ks * 64 + kgrp * 16) ^ ((arow & 7) << 4)));
        #pragma unroll
        for (int n = 0; n < 8; ++n) {
            const int brow = n * 16 + lrow;
            const bf16x8 b = *(const bf16x8*)((const char*)Wl +
                ((brow * 256 + ks * 64 + kgrp * 16) ^ ((brow & 7) << 4)));
            acc[n] = __builtin_amdgcn_mfma_f32_16x16x32_bf16(a, b, acc[n], 0, 0, 0);
        }
    }

    // C/D layout: col = lane&15, row = (lane>>4)*4 + i
    if (second) {   // f32 direct store: 16-lane groups write 64B segments
        #pragma unroll
        for (int n = 0; n < 8; ++n) {
            const float bv = bias[n * 16 + lrow];
            #pragma unroll
            for (int i = 0; i < 4; ++i) {
                const size_t r = row0 + rw + kgrp * 4 + i;
                out2[r * D + n * 16 + lrow] = acc[n][i] + bv;
            }
        }
        return;
    }

    __syncthreads();
    #pragma unroll
    for (int n = 0; n < 8; ++n) {
        const float bv = bias[n * 16 + lrow];
        #pragma unroll
        for (int i = 0; i < 4; ++i) {
            const int r = rw + kgrp * 4 + i;
            const int cb = (r * 256 + (n * 16 + lrow) * 2) ^ ((r & 7) << 4);
            *(unsigned short*)((char*)Al + cb) = f2bf(acc[n][i] + bv);
        }
    }
    __syncthreads();
    {
        float4* dst = (float4*)(outbf + row0 * D);
        #pragma unroll
        for (int m = 0; m < 4; ++m) {
            const int c = m * 256 + t;
            const int r = c >> 4;
            dst[c] = *(const float4*)((const char*)Al + ((c * 16) ^ ((r & 7) << 4)));
        }
    }
}

// ---------------------------------------------------------------------------
// aggregate v4: proven gather layout (dq=t&31 -> full 256B Etr rows/instr),
// in-wave shfl_xor(32) fold -> ps[4] LDS -> final. 20.5 KB LDS, 2 barriers.
// ---------------------------------------------------------------------------
__global__ __launch_bounds__(256) void aggregate(
    const int* __restrict__ i_idx, const int* __restrict__ u_idx,
    const int* __restrict__ adj_e, const int* __restrict__ adj_r,
    const unsigned short* __restrict__ Etr, const float* __restrict__ rel_embs,
    const float* __restrict__ hW,  const float* __restrict__ h0,
    float* __restrict__ g_out)
{
    __shared__ float tt[NREL * D];    // 16 KB
    __shared__ int ents[KNB];
    __shared__ int rels[KNB];
    __shared__ float ps[4][D];
    __shared__ float pq[4][D];

    const int t = threadIdx.x;
    const int b = blockIdx.x & (B - 1);
    const int j = blockIdx.x >> 12;
    const size_t rowbase = ((size_t)j * B + b) * D;
    const int idx = j ? u_idx[b] : i_idx[b];

    if (t < KNB) {
        ents[t] = adj_e[(size_t)idx * KNB + t] * (D * 2);
        rels[t] = adj_r[(size_t)idx * KNB + t] * (D * 4);
    }
    {
        const float4 hv = *(const float4*)&hW[rowbase + (t & 31) * 4];
        const float4* re4 = (const float4*)rel_embs;
        #pragma unroll
        for (int c = 0; c < 4; ++c) {
            const int m4 = t + c * 256;
            const float4 r = re4[m4];
            float4 o;
            o.x = fast_tanh(hv.x + r.x);
            o.y = fast_tanh(hv.y + r.y);
            o.z = fast_tanh(hv.z + r.z);
            o.w = fast_tanh(hv.w + r.w);
            *(float4*)&tt[m4 * 4] = o;
        }
    }
    __syncthreads();

    const int dq  = t & 31;
    const int grp = t >> 5;
    const char* Eb = (const char*)Etr + dq * 8;
    const char* tb = (const char*)tt  + dq * 16;

    float s0 = 0.f, s1 = 0.f, s2 = 0.f, s3 = 0.f;
    float q0 = 0.f, q1 = 0.f, q2 = 0.f, q3 = 0.f;
    #pragma unroll
    for (int it = 0; it < 8; ++it) {
        const int k = grp + it * 8;
        const uint2  ev = *(const uint2*)(Eb + ents[k]);
        const float4 tv = *(const float4*)(tb + rels[k]);
        const float v0 = bfu_lo(ev.x) * tv.x;
        const float v1 = bfu_hi(ev.x) * tv.y;
        const float v2 = bfu_lo(ev.y) * tv.z;
        const float v3 = bfu_hi(ev.y) * tv.w;
        s0 += v0; s1 += v1; s2 += v2; s3 += v3;
        q0 = fmaf(v0, v0, q0); q1 = fmaf(v1, v1, q1);
        q2 = fmaf(v2, v2, q2); q3 = fmaf(v3, v3, q3);
    }
    s0 += __shfl_xor(s0, 32); s1 += __shfl_xor(s1, 32);
    s2 += __shfl_xor(s2, 32); s3 += __shfl_xor(s3, 32);
    q0 += __shfl_xor(q0, 32); q1 += __shfl_xor(q1, 32);
    q2 += __shfl_xor(q2, 32); q3 += __shfl_xor(q3, 32);

    const int wv = t >> 6;
    if ((t & 63) < 32) {
        *(float4*)&ps[wv][dq * 4] = make_float4(s0, s1, s2, s3);
        *(float4*)&pq[wv][dq * 4] = make_float4(q0, q1, q2, q3);
    }
    __syncthreads();

    if (t < D) {
        const float ss = ps[0][t] + ps[1][t] + ps[2][t] + ps[3][t];
        const float qq = pq[0][t] + pq[1][t] + pq[2][t] + pq[3][t];
        g_out[rowbase + t] = h0[rowbase + t] + ss * ss - qq;
    }
}

// ---------------------------------------------------------------------------
// gemm_fin: block handles 16 b's = rows {b0..b0+15} (j=0) + {B+b0..} (j=1).
// o = h0 + lrelu(gb @ W1 + b1); epilogue: per-row dot with wl segment,
// 32-lane shfl reduce, out[b] = wl_b + dot(j0,wl[128:]) + dot(j1,wl[0:128]).
// hfin never hits global memory.
// ---------------------------------------------------------------------------
__global__ __launch_bounds__(256) void gemm_fin(
    const float* __restrict__ gb, const float* __restrict__ W,
    const float* __restrict__ bias, const float* __restrict__ h0,
    const float* __restrict__ wl_w, const float* __restrict__ wl_b,
    float* __restrict__ out)
{
    __shared__ float Wl[128 * 128];   // 64 KB
    __shared__ float inl[32 * 128];   // 16 KB
    __shared__ float rowdot[32];
    const int t = threadIdx.x;
    const int b0 = blockIdx.x * 16;

    {
        const float4* W4 = (const float4*)W;
        float4* Wl4 = (float4*)Wl;
        #pragma unroll
        for (int m = 0; m < 16; ++m) Wl4[t + m * 256] = W4[t + m * 256];
    }
    {   // rows 0-15 <- gb[b0+r], rows 16-31 <- gb[B+b0+(r-16)]
        const float4* gb4 = (const float4*)gb;
        float4* inl4 = (float4*)inl;
        #pragma unroll
        for (int m = 0; m < 4; ++m) {
            const int c = m * 256 + t;
            const int r = c >> 5;
            const size_t grow = (r < 16) ? (size_t)(b0 + r) : (size_t)(B + b0 + r - 16);
            inl4[c] = gb4[grow * 32 + (c & 31)];
        }
    }
    __syncthreads();

    const int c0 = (t & 31) * 4;
    const int r0 = (t >> 5) * 4;

    float acc[4][4];
    {
        float4 bv = *(const float4*)&bias[c0];
        #pragma unroll
        for (int i = 0; i < 4; ++i) {
            acc[i][0] = bv.x; acc[i][1] = bv.y; acc[i][2] = bv.z; acc[i][3] = bv.w;
        }
    }

    for (int k = 0; k < 128; k += 4) {
        float4 a[4], w[4];
        #pragma unroll
        for (int i = 0; i < 4; ++i) a[i] = *(const float4*)&inl[(r0 + i) * D + k];
        #pragma unroll
        for (int kk = 0; kk < 4; ++kk) w[kk] = *(const float4*)&Wl[(k + kk) * D + c0];
        #pragma unroll
        for (int i = 0; i < 4; ++i) {
            const float* ai = (const float*)&a[i];
            #pragma unroll
            for (int kk = 0; kk < 4; ++kk) {
                acc[i][0] = fmaf(ai[kk], w[kk].x, acc[i][0]);
                acc[i][1] = fmaf(ai[kk], w[kk].y, acc[i][1]);
                acc[i][2] = fmaf(ai[kk], w[kk].z, acc[i][2]);
                acc[i][3] = fmaf(ai[kk], w[kk].w, acc[i][3]);
            }
        }
    }

    // epilogue: hfin row-dot with wl.  j=0 rows (r<16) -> wl[128:256],
    // j=1 rows -> wl[0:128].  r0 is block-uniform within a thread.
    const int seg = (r0 < 16) ? 128 : 0;
    const float4 wv = *(const float4*)&wl_w[seg + c0];
    float pr[4];
    #pragma unroll
    for (int i = 0; i < 4; ++i) {
        const int r = r0 + i;
        const size_t grow = (r < 16) ? (size_t)(b0 + r) : (size_t)(B + b0 + r - 16);
        const float4 ad = *(const float4*)&h0[grow * D + c0];
        float4 o;
        o.x = ad.x + (acc[i][0] >= 0.f ? acc[i][0] : 0.2f * acc[i][0]);
        o.y = ad.y + (acc[i][1] >= 0.f ? acc[i][1] : 0.2f * acc[i][1]);
        o.z = ad.z + (acc[i][2] >= 0.f ? acc[i][2] : 0.2f * acc[i][2]);
        o.w = ad.w + (acc[i][3] >= 0.f ? acc[i][3] : 0.2f * acc[i][3]);
        pr[i] = o.x * wv.x + o.y * wv.y + o.z * wv.z + o.w * wv.w;
    }
    #pragma unroll
    for (int off = 1; off <= 16; off <<= 1) {
        pr[0] += __shfl_xor(pr[0], off);
        pr[1] += __shfl_xor(pr[1], off);
        pr[2] += __shfl_xor(pr[2], off);
        pr[3] += __shfl_xor(pr[3], off);
    }
    if ((t & 31) == 0) {
        rowdot[r0]     = pr[0];
        rowdot[r0 + 1] = pr[1];
        rowdot[r0 + 2] = pr[2];
        rowdot[r0 + 3] = pr[3];
    }
    __syncthreads();
    if (t < 16) out[b0 + t] = wl_b[0] + rowdot[t + 16] + rowdot[t];
}

extern "C" void kernel_launch(void* const* d_in, const int* in_sizes, int n_in,
                              void* d_out, int out_size, void* d_ws, size_t ws_size,
                              hipStream_t stream) {
    const int*   u        = (const int*)d_in[0];
    const int*   ii       = (const int*)d_in[1];
    const int*   adj_e    = (const int*)d_in[2];
    const int*   adj_r    = (const int*)d_in[3];
    const float* embs     = (const float*)d_in[4];
    const float* rel_embs = (const float*)d_in[5];
    const float* gamma    = (const float*)d_in[6];
    const float* beta     = (const float*)d_in[7];
    const float* mean     = (const float*)d_in[8];
    const float* var      = (const float*)d_in[9];
    const float* Wr1_w    = (const float*)d_in[10];
    const float* Wr1_b    = (const float*)d_in[11];
    const float* W1_w     = (const float*)d_in[12];
    const float* W1_b     = (const float*)d_in[13];
    const float* wl_w     = (const float*)d_in[14];
    const float* wl_b     = (const float*)d_in[15];
    float* out = (float*)d_out;

    const int n_ent = in_sizes[2] / KNB;    // 200000
    const int nb1 = n_ent / 64;             // 3125

    char* p = (char*)d_ws;
    unsigned short* Etr = (unsigned short*)p;           p += (size_t)n_ent * D * 2;   // 51.2 MB
    unsigned short* Wt  = (unsigned short*)p;           p += (size_t)D * D * 2;       // 32 KB
    float* h0   = (float*)p;                            p += (size_t)2 * B * D * 4;
    float* hWb  = (float*)p;                            p += (size_t)2 * B * D * 4;
    float* gb   = (float*)p;

    // 1. h0 = bn(embs[{i,u}])  +  Wt = bf16(Wr1^T)
    prep<<<1025, 256, 0, stream>>>(ii, u, embs, gamma, beta, mean, var, h0, Wr1_w, Wt);
    // 2. Etr = bf16(embs @ Wr1 + b)  AND  hW = h0 @ Wr1 + b   (one MFMA kernel)
    gemm_etr<<<nb1 + (2 * B) / 64, 256, 0, stream>>>(embs, Wt, Wr1_b, Etr, h0, hWb, nb1);
    // 3. FM aggregation -> g = h0 + Nh
    aggregate<<<2 * B, 256, 0, stream>>>(ii, u, adj_e, adj_r, Etr, rel_embs, hWb, h0, gb);
    // 4. hfin = h0 + lrelu(g @ W1 + b) fused with out = [u_e,h]@wl + wl_b
    gemm_fin<<<B / 16, 256, 0, stream>>>(gb, W1_w, W1_b, h0, wl_w, wl_b, out);
}

// Round 7
// 78.639 us; speedup vs baseline: 1.3358x; 1.0481x over previous
//
#include <hip/hip_runtime.h>

#define B     4096
#define KNB   64
#define D     128
#define NREL  32
#define EPS   1e-5f

typedef __attribute__((ext_vector_type(8))) short bf16x8;
typedef __attribute__((ext_vector_type(4))) float f32x4;

__device__ inline unsigned short f2bf(float f) {
    unsigned u = __float_as_uint(f);
    return (unsigned short)((u + 0x7FFFu + ((u >> 16) & 1u)) >> 16);
}
// HW packed convert, RTNE — bit-identical to f2bf, 1 VALU op per 2 floats.
__device__ inline unsigned cvt_pk_bf16(float lo, float hi) {
    unsigned r;
    asm("v_cvt_pk_bf16_f32 %0, %1, %2" : "=v"(r) : "v"(lo), "v"(hi));
    return r;
}
__device__ inline unsigned short cvt1_bf16(float f) {
    return (unsigned short)(cvt_pk_bf16(f, f) & 0xFFFFu);
}
__device__ inline float bfu_lo(unsigned u) { return __uint_as_float(u << 16); }
__device__ inline float bfu_hi(unsigned u) { return __uint_as_float(u & 0xFFFF0000u); }

// tanh(x) = 1 - 2/(exp(2x)+1), exp via native v_exp_f32. |err| ~1e-6.
__device__ inline float fast_tanh(float x) {
    float e = __builtin_amdgcn_exp2f(x * 2.885390082f);   // 2*log2(e)
    return 1.f - 2.f * __builtin_amdgcn_rcpf(e + 1.f);
}

// ---------------------------------------------------------------------------
// prep: blocks 0..1023 -> h0 = bn(embs[{i,u}]);  block 1024 -> Wt = bf16(W^T)
// ---------------------------------------------------------------------------
__global__ __launch_bounds__(256) void prep(
    const int* __restrict__ i_idx, const int* __restrict__ u_idx,
    const float* __restrict__ embs,
    const float* __restrict__ gamma, const float* __restrict__ beta,
    const float* __restrict__ mean,  const float* __restrict__ var,
    float* __restrict__ h0,
    const float* __restrict__ W, unsigned short* __restrict__ Wt)
{
    const int t = threadIdx.x;
    if (blockIdx.x == 1024) {   // wt_prep
        #pragma unroll
        for (int m = 0; m < 64; ++m) {
            const int idx = m * 256 + t;
            const int k = idx >> 7, n = idx & 127;
            Wt[n * D + k] = f2bf(W[idx]);
        }
        return;
    }
    const int tid = blockIdx.x * 256 + t;      // 0 .. 2*B*32-1
    const int d4 = tid & 31;
    const int b  = (tid >> 5) & (B - 1);
    const int j  = tid >> 17;
    const int idx = j ? u_idx[b] : i_idx[b];

    const int d0 = d4 * 4;
    float4 x = *(const float4*)&embs[(size_t)idx * D + d0];
    float4 m = *(const float4*)&mean[d0];
    float4 v = *(const float4*)&var[d0];
    float4 g = *(const float4*)&gamma[d0];
    float4 bt = *(const float4*)&beta[d0];

    float4 o;
    o.x = (x.x - m.x) * g.x * rsqrtf(v.x + EPS) + bt.x;
    o.y = (x.y - m.y) * g.y * rsqrtf(v.y + EPS) + bt.y;
    o.z = (x.z - m.z) * g.z * rsqrtf(v.z + EPS) + bt.z;
    o.w = (x.w - m.w) * g.w * rsqrtf(v.w + EPS) + bt.w;

    *(float4*)&h0[(size_t)tid * 4] = o;
}

// ---------------------------------------------------------------------------
// MFMA GEMM, 16x16x32 bf16, tile 64 rows x 128 cols, 4 waves.
// blocks <  nb1 : Etr  = bf16( in  @ W + bias )  (bf16 bounce-store)
// blocks >= nb1 : hW   =        in2 @ W + bias   (f32 direct store)
// ---------------------------------------------------------------------------
__global__ __launch_bounds__(256) void gemm_etr(
    const float* __restrict__ in, const unsigned short* __restrict__ Wt,
    const float* __restrict__ bias, unsigned short* __restrict__ outbf,
    const float* __restrict__ in2, float* __restrict__ out2, int nb1)
{
    __shared__ unsigned short Al[64 * 128];    // 16 KB
    __shared__ unsigned short Wl[128 * 128];   // 32 KB

    const int t = threadIdx.x;
    const bool second = (int)blockIdx.x >= nb1;
    const float* src = second ? in2 : in;
    const size_t row0 = (size_t)(second ? (int)blockIdx.x - nb1 : (int)blockIdx.x) * 64;

    {
        const float4* w4 = (const float4*)Wt;
        #pragma unroll
        for (int m = 0; m < 8; ++m) {
            const int c = m * 256 + t;
            const int n = c >> 4;
            float4 v = w4[c];
            *(float4*)((char*)Wl + ((c * 16) ^ ((n & 7) << 4))) = v;
        }
    }
    {
        #pragma unroll
        for (int m = 0; m < 4; ++m) {
            const int c = m * 256 + t;
            const int r = c >> 4;
            const int k0 = (c & 15) * 8;
            const float4* s = (const float4*)&src[(row0 + r) * D + k0];
            const float4 x = s[0], y = s[1];
            uint4 h;
            h.x = cvt_pk_bf16(x.x, x.y);
            h.y = cvt_pk_bf16(x.z, x.w);
            h.z = cvt_pk_bf16(y.x, y.y);
            h.w = cvt_pk_bf16(y.z, y.w);
            *(uint4*)((char*)Al + ((r * 256 + k0 * 2) ^ ((r & 7) << 4))) = h;
        }
    }
    __syncthreads();

    const int wv   = t >> 6;
    const int lane = t & 63;
    const int rw   = wv * 16;
    const int lrow = lane & 15;
    const int kgrp = lane >> 4;

    f32x4 acc[8];
    #pragma unroll
    for (int n = 0; n < 8; ++n) acc[n] = (f32x4){0.f, 0.f, 0.f, 0.f};

    #pragma unroll
    for (int ks = 0; ks < 4; ++ks) {
        const int arow = rw + lrow;
        const bf16x8 a = *(const bf16x8*)((const char*)Al +
            ((arow * 256 + ks * 64 + kgrp * 16) ^ ((arow & 7) << 4)));
        #pragma unroll
        for (int n = 0; n < 8; ++n) {
            const int brow = n * 16 + lrow;
            const bf16x8 b = *(const bf16x8*)((const char*)Wl +
                ((brow * 256 + ks * 64 + kgrp * 16) ^ ((brow & 7) << 4)));
            acc[n] = __builtin_amdgcn_mfma_f32_16x16x32_bf16(a, b, acc[n], 0, 0, 0);
        }
    }

    // C/D layout: col = lane&15, row = (lane>>4)*4 + i
    if (second) {   // f32 direct store
        #pragma unroll
        for (int n = 0; n < 8; ++n) {
            const float bv = bias[n * 16 + lrow];
            #pragma unroll
            for (int i = 0; i < 4; ++i) {
                const size_t r = row0 + rw + kgrp * 4 + i;
                out2[r * D + n * 16 + lrow] = acc[n][i] + bv;
            }
        }
        return;
    }

    __syncthreads();
    #pragma unroll
    for (int n = 0; n < 8; ++n) {
        const float bv = bias[n * 16 + lrow];
        #pragma unroll
        for (int i = 0; i < 4; ++i) {
            const int r = rw + kgrp * 4 + i;
            const int cb = (r * 256 + (n * 16 + lrow) * 2) ^ ((r & 7) << 4);
            *(unsigned short*)((char*)Al + cb) = cvt1_bf16(acc[n][i] + bv);
        }
    }
    __syncthreads();
    {
        float4* dst = (float4*)(outbf + row0 * D);
        #pragma unroll
        for (int m = 0; m < 4; ++m) {
            const int c = m * 256 + t;
            const int r = c >> 4;
            dst[c] = *(const float4*)((const char*)Al + ((c * 16) ^ ((r & 7) << 4)));
        }
    }
}

// ---------------------------------------------------------------------------
// aggregate v5: barrier split — gathers issue BEFORE the tanh-table build so
// L3 latency hides under the trans-heavy table pass (T14 intra-block).
// Gather layout unchanged (dq=t&31 -> full 256B Etr rows per half-wave).
// ---------------------------------------------------------------------------
__global__ __launch_bounds__(256) void aggregate(
    const int* __restrict__ i_idx, const int* __restrict__ u_idx,
    const int* __restrict__ adj_e, const int* __restrict__ adj_r,
    const unsigned short* __restrict__ Etr, const float* __restrict__ rel_embs,
    const float* __restrict__ hW,  const float* __restrict__ h0,
    float* __restrict__ g_out)
{
    __shared__ float tt[NREL * D];    // 16 KB
    __shared__ int ents[KNB];
    __shared__ int rels[KNB];
    __shared__ float ps[4][D];
    __shared__ float pq[4][D];

    const int t = threadIdx.x;
    const int b = blockIdx.x & (B - 1);
    const int j = blockIdx.x >> 12;
    const size_t rowbase = ((size_t)j * B + b) * D;
    const int idx = j ? u_idx[b] : i_idx[b];

    // issue hW chunk early (needed for table build)
    const float4 hv = *(const float4*)&hW[rowbase + (t & 31) * 4];

    if (t < KNB) {
        ents[t] = adj_e[(size_t)idx * KNB + t] * (D * 2);
        rels[t] = adj_r[(size_t)idx * KNB + t] * (D * 4);
    }
    __syncthreads();   // ents/rels ready

    const int dq  = t & 31;
    const int grp = t >> 5;
    const char* Eb = (const char*)Etr + dq * 8;
    const char* tb = (const char*)tt  + dq * 16;

    // issue ALL 8 random gathers now; their ~700ns L3 latency hides under
    // the tanh-table pass below.
    uint2 ev[8];
    int rk[8];
    #pragma unroll
    for (int it = 0; it < 8; ++it) {
        const int k = grp + it * 8;
        ev[it] = *(const uint2*)(Eb + ents[k]);
        rk[it] = rels[k];
    }

    // tanh table: 4 float4/thread (trans-heavy)
    {
        const float4* re4 = (const float4*)rel_embs;
        #pragma unroll
        for (int c = 0; c < 4; ++c) {
            const int m4 = t + c * 256;
            const float4 r = re4[m4];
            float4 o;
            o.x = fast_tanh(hv.x + r.x);
            o.y = fast_tanh(hv.y + r.y);
            o.z = fast_tanh(hv.z + r.z);
            o.w = fast_tanh(hv.w + r.w);
            *(float4*)&tt[m4 * 4] = o;
        }
    }
    __syncthreads();   // tt ready

    float s0 = 0.f, s1 = 0.f, s2 = 0.f, s3 = 0.f;
    float q0 = 0.f, q1 = 0.f, q2 = 0.f, q3 = 0.f;
    #pragma unroll
    for (int it = 0; it < 8; ++it) {
        const float4 tv = *(const float4*)(tb + rk[it]);
        const float v0 = bfu_lo(ev[it].x) * tv.x;
        const float v1 = bfu_hi(ev[it].x) * tv.y;
        const float v2 = bfu_lo(ev[it].y) * tv.z;
        const float v3 = bfu_hi(ev[it].y) * tv.w;
        s0 += v0; s1 += v1; s2 += v2; s3 += v3;
        q0 = fmaf(v0, v0, q0); q1 = fmaf(v1, v1, q1);
        q2 = fmaf(v2, v2, q2); q3 = fmaf(v3, v3, q3);
    }
    s0 += __shfl_xor(s0, 32); s1 += __shfl_xor(s1, 32);
    s2 += __shfl_xor(s2, 32); s3 += __shfl_xor(s3, 32);
    q0 += __shfl_xor(q0, 32); q1 += __shfl_xor(q1, 32);
    q2 += __shfl_xor(q2, 32); q3 += __shfl_xor(q3, 32);

    const int wv = t >> 6;
    if ((t & 63) < 32) {
        *(float4*)&ps[wv][dq * 4] = make_float4(s0, s1, s2, s3);
        *(float4*)&pq[wv][dq * 4] = make_float4(q0, q1, q2, q3);
    }
    __syncthreads();

    if (t < D) {
        const float ss = ps[0][t] + ps[1][t] + ps[2][t] + ps[3][t];
        const float qq = pq[0][t] + pq[1][t] + pq[2][t] + pq[3][t];
        g_out[rowbase + t] = h0[rowbase + t] + ss * ss - qq;
    }
}

// ---------------------------------------------------------------------------
// gemm_fin: block handles 16 b's = rows {b0..b0+15} (j=0) + {B+b0..} (j=1).
// o = h0 + lrelu(gb @ W1 + b1); epilogue: per-row dot with wl segment,
// 32-lane shfl reduce, out[b] = wl_b + dot(j0,wl[128:]) + dot(j1,wl[0:128]).
// ---------------------------------------------------------------------------
__global__ __launch_bounds__(256) void gemm_fin(
    const float* __restrict__ gb, const float* __restrict__ W,
    const float* __restrict__ bias, const float* __restrict__ h0,
    const float* __restrict__ wl_w, const float* __restrict__ wl_b,
    float* __restrict__ out)
{
    __shared__ float Wl[128 * 128];   // 64 KB
    __shared__ float inl[32 * 128];   // 16 KB
    __shared__ float rowdot[32];
    const int t = threadIdx.x;
    const int b0 = blockIdx.x * 16;

    {
        const float4* W4 = (const float4*)W;
        float4* Wl4 = (float4*)Wl;
        #pragma unroll
        for (int m = 0; m < 16; ++m) Wl4[t + m * 256] = W4[t + m * 256];
    }
    {
        const float4* gb4 = (const float4*)gb;
        float4* inl4 = (float4*)inl;
        #pragma unroll
        for (int m = 0; m < 4; ++m) {
            const int c = m * 256 + t;
            const int r = c >> 5;
            const size_t grow = (r < 16) ? (size_t)(b0 + r) : (size_t)(B + b0 + r - 16);
            inl4[c] = gb4[grow * 32 + (c & 31)];
        }
    }
    __syncthreads();

    const int c0 = (t & 31) * 4;
    const int r0 = (t >> 5) * 4;

    float acc[4][4];
    {
        float4 bv = *(const float4*)&bias[c0];
        #pragma unroll
        for (int i = 0; i < 4; ++i) {
            acc[i][0] = bv.x; acc[i][1] = bv.y; acc[i][2] = bv.z; acc[i][3] = bv.w;
        }
    }

    for (int k = 0; k < 128; k += 4) {
        float4 a[4], w[4];
        #pragma unroll
        for (int i = 0; i < 4; ++i) a[i] = *(const float4*)&inl[(r0 + i) * D + k];
        #pragma unroll
        for (int kk = 0; kk < 4; ++kk) w[kk] = *(const float4*)&Wl[(k + kk) * D + c0];
        #pragma unroll
        for (int i = 0; i < 4; ++i) {
            const float* ai = (const float*)&a[i];
            #pragma unroll
            for (int kk = 0; kk < 4; ++kk) {
                acc[i][0] = fmaf(ai[kk], w[kk].x, acc[i][0]);
                acc[i][1] = fmaf(ai[kk], w[kk].y, acc[i][1]);
                acc[i][2] = fmaf(ai[kk], w[kk].z, acc[i][2]);
                acc[i][3] = fmaf(ai[kk], w[kk].w, acc[i][3]);
            }
        }
    }

    const int seg = (r0 < 16) ? 128 : 0;
    const float4 wv = *(const float4*)&wl_w[seg + c0];
    float pr[4];
    #pragma unroll
    for (int i = 0; i < 4; ++i) {
        const int r = r0 + i;
        const size_t grow = (r < 16) ? (size_t)(b0 + r) : (size_t)(B + b0 + r - 16);
        const float4 ad = *(const float4*)&h0[grow * D + c0];
        float4 o;
        o.x = ad.x + (acc[i][0] >= 0.f ? acc[i][0] : 0.2f * acc[i][0]);
        o.y = ad.y + (acc[i][1] >= 0.f ? acc[i][1] : 0.2f * acc[i][1]);
        o.z = ad.z + (acc[i][2] >= 0.f ? acc[i][2] : 0.2f * acc[i][2]);
        o.w = ad.w + (acc[i][3] >= 0.f ? acc[i][3] : 0.2f * acc[i][3]);
        pr[i] = o.x * wv.x + o.y * wv.y + o.z * wv.z + o.w * wv.w;
    }
    #pragma unroll
    for (int off = 1; off <= 16; off <<= 1) {
        pr[0] += __shfl_xor(pr[0], off);
        pr[1] += __shfl_xor(pr[1], off);
        pr[2] += __shfl_xor(pr[2], off);
        pr[3] += __shfl_xor(pr[3], off);
    }
    if ((t & 31) == 0) {
        rowdot[r0]     = pr[0];
        rowdot[r0 + 1] = pr[1];
        rowdot[r0 + 2] = pr[2];
        rowdot[r0 + 3] = pr[3];
    }
    __syncthreads();
    if (t < 16) out[b0 + t] = wl_b[0] + rowdot[t + 16] + rowdot[t];
}

extern "C" void kernel_launch(void* const* d_in, const int* in_sizes, int n_in,
                              void* d_out, int out_size, void* d_ws, size_t ws_size,
                              hipStream_t stream) {
    const int*   u        = (const int*)d_in[0];
    const int*   ii       = (const int*)d_in[1];
    const int*   adj_e    = (const int*)d_in[2];
    const int*   adj_r    = (const int*)d_in[3];
    const float* embs     = (const float*)d_in[4];
    const float* rel_embs = (const float*)d_in[5];
    const float* gamma    = (const float*)d_in[6];
    const float* beta     = (const float*)d_in[7];
    const float* mean     = (const float*)d_in[8];
    const float* var      = (const float*)d_in[9];
    const float* Wr1_w    = (const float*)d_in[10];
    const float* Wr1_b    = (const float*)d_in[11];
    const float* W1_w     = (const float*)d_in[12];
    const float* W1_b     = (const float*)d_in[13];
    const float* wl_w     = (const float*)d_in[14];
    const float* wl_b     = (const float*)d_in[15];
    float* out = (float*)d_out;

    const int n_ent = in_sizes[2] / KNB;    // 200000
    const int nb1 = n_ent / 64;             // 3125

    char* p = (char*)d_ws;
    unsigned short* Etr = (unsigned short*)p;           p += (size_t)n_ent * D * 2;   // 51.2 MB
    unsigned short* Wt  = (unsigned short*)p;           p += (size_t)D * D * 2;       // 32 KB
    float* h0   = (float*)p;                            p += (size_t)2 * B * D * 4;
    float* hWb  = (float*)p;                            p += (size_t)2 * B * D * 4;
    float* gb   = (float*)p;

    // 1. h0 = bn(embs[{i,u}])  +  Wt = bf16(Wr1^T)
    prep<<<1025, 256, 0, stream>>>(ii, u, embs, gamma, beta, mean, var, h0, Wr1_w, Wt);
    // 2. Etr = bf16(embs @ Wr1 + b)  AND  hW = h0 @ Wr1 + b   (one MFMA kernel)
    gemm_etr<<<nb1 + (2 * B) / 64, 256, 0, stream>>>(embs, Wt, Wr1_b, Etr, h0, hWb, nb1);
    // 3. FM aggregation -> g = h0 + Nh
    aggregate<<<2 * B, 256, 0, stream>>>(ii, u, adj_e, adj_r, Etr, rel_embs, hWb, h0, gb);
    // 4. hfin = h0 + lrelu(g @ W1 + b) fused with out = [u_e,h]@wl + wl_b
    gemm_fin<<<B / 16, 256, 0, stream>>>(gb, W1_w, W1_b, h0, wl_w, wl_b, out);
}